// Round 1
// baseline (46010.809 us; speedup 1.0000x reference)
//
#include <hip/hip_runtime.h>
#include <hip/hip_bf16.h>

// MultilayerGRU: B=128, S=512, H=1024, L=2, O=1024
// Strategy:
//   - cast all weights to bf16 (MFMA inputs), f32 accumulate
//   - precompute gx0[s][b][3H] = x @ Wx0^T + bh0  (big parallel GEMM, bf16 out)
//   - 512 sequential steps x 4 fused MFMA kernels (zr-gemm+sigmoid, g-gemm+tanh+update) x 2 layers
//   - final big GEMM h1_all @ Why^T + by -> layer_output; copy h finals -> hidden_state

typedef __bf16 bf16;
typedef __attribute__((ext_vector_type(8))) __bf16 bf16x8;
typedef __attribute__((ext_vector_type(4))) __bf16 bf16x4;
typedef __attribute__((ext_vector_type(4))) float f32x4;

#define MFMA16(a, b, c) __builtin_amdgcn_mfma_f32_16x16x32_bf16(a, b, c, 0, 0, 0)

static __device__ __forceinline__ bf16x8 ldfrag(const bf16* p) {
  return *reinterpret_cast<const bf16x8*>(p);
}

// ---------------- weight cast ----------------
__global__ void k_cast4(const float* __restrict__ s, bf16* __restrict__ d, int n4) {
  int i = blockIdx.x * blockDim.x + threadIdx.x;
  int st = gridDim.x * blockDim.x;
  for (; i < n4; i += st) {
    float4 v = reinterpret_cast<const float4*>(s)[i];
    bf16x4 o = {(bf16)v.x, (bf16)v.y, (bf16)v.z, (bf16)v.w};
    *reinterpret_cast<bf16x4*>(d + (size_t)i * 4) = o;
  }
}

// ---------------- gx0 = x @ Wx0^T + bh0 ----------------
// x: [B][S][H] f32, rows m = s*128+b ; wx0: [3072][1024] bf16 ; out gx0: [S*B][3072] bf16
__global__ __launch_bounds__(256) void k_gx0(const float* __restrict__ x,
                                             const bf16* __restrict__ wx0,
                                             const float* __restrict__ bh,
                                             bf16* __restrict__ gx0) {
  const int lane = threadIdx.x & 63;
  const int gw = blockIdx.x * 4 + (threadIdx.x >> 6);
  const int NT = 3072 / 64;  // 48
  const int tm = gw / NT, tn = gw % NT;
  const int m0 = tm * 64, n0 = tn * 64;
  const int r = lane & 15, kq = lane >> 4;
  f32x4 acc[4][4] = {};
  for (int k0 = 0; k0 < 1024; k0 += 32) {
    const int k = k0 + kq * 8;
    bf16x8 a[4], b[4];
#pragma unroll
    for (int mi = 0; mi < 4; ++mi) {
      const int m = m0 + mi * 16 + r;
      const int bb = m & 127, s = m >> 7;
      const float* xp = x + ((size_t)(bb * 512 + s)) * 1024 + k;
      float4 lo = *reinterpret_cast<const float4*>(xp);
      float4 hi = *reinterpret_cast<const float4*>(xp + 4);
      bf16x8 av;
      av[0] = (bf16)lo.x; av[1] = (bf16)lo.y; av[2] = (bf16)lo.z; av[3] = (bf16)lo.w;
      av[4] = (bf16)hi.x; av[5] = (bf16)hi.y; av[6] = (bf16)hi.z; av[7] = (bf16)hi.w;
      a[mi] = av;
    }
#pragma unroll
    for (int ni = 0; ni < 4; ++ni)
      b[ni] = ldfrag(wx0 + (size_t)(n0 + ni * 16 + r) * 1024 + k);
#pragma unroll
    for (int mi = 0; mi < 4; ++mi)
#pragma unroll
      for (int ni = 0; ni < 4; ++ni) acc[mi][ni] = MFMA16(a[mi], b[ni], acc[mi][ni]);
  }
#pragma unroll
  for (int mi = 0; mi < 4; ++mi) {
#pragma unroll
    for (int j = 0; j < 4; ++j) {
      const int m = m0 + mi * 16 + kq * 4 + j;
#pragma unroll
      for (int ni = 0; ni < 4; ++ni) {
        const int col = n0 + ni * 16 + r;
        gx0[(size_t)m * 3072 + col] = (bf16)(acc[mi][ni][j] + bh[col]);
      }
    }
  }
}

// ---------------- per-step z/r kernel ----------------
// pre = A1@B1^T [+ A2@B2^T] + addend ; z=sigmoid -> zout (cols 0..1023)
// r=sigmoid -> rhout = r * hmast (cols 1024..2047)
__global__ __launch_bounds__(256) void k_zr(const bf16* __restrict__ A1, const bf16* __restrict__ B1,
                                            const bf16* __restrict__ A2, const bf16* __restrict__ B2,
                                            const bf16* __restrict__ gx,    // [128][3072] addend, or null
                                            const float* __restrict__ bias, // per-col addend (if gx null)
                                            const float* __restrict__ hmast,
                                            float* __restrict__ zout,
                                            bf16* __restrict__ rhout) {
  const int lane = threadIdx.x & 63;
  const int gw = blockIdx.x * 4 + (threadIdx.x >> 6);
  const int tm = gw >> 6, tn = gw & 63;  // N=2048 -> 64 n-tiles of 32
  const int m0 = tm * 16, n0 = tn * 32;
  const int r = lane & 15, kq = lane >> 4;
  f32x4 acc[2] = {};
  for (int k0 = 0; k0 < 1024; k0 += 32) {
    const int k = k0 + kq * 8;
    bf16x8 a = ldfrag(A1 + (size_t)(m0 + r) * 1024 + k);
#pragma unroll
    for (int ni = 0; ni < 2; ++ni) {
      bf16x8 b = ldfrag(B1 + (size_t)(n0 + ni * 16 + r) * 1024 + k);
      acc[ni] = MFMA16(a, b, acc[ni]);
    }
  }
  if (A2) {
    for (int k0 = 0; k0 < 1024; k0 += 32) {
      const int k = k0 + kq * 8;
      bf16x8 a = ldfrag(A2 + (size_t)(m0 + r) * 1024 + k);
#pragma unroll
      for (int ni = 0; ni < 2; ++ni) {
        bf16x8 b = ldfrag(B2 + (size_t)(n0 + ni * 16 + r) * 1024 + k);
        acc[ni] = MFMA16(a, b, acc[ni]);
      }
    }
  }
#pragma unroll
  for (int ni = 0; ni < 2; ++ni) {
    const int col = n0 + ni * 16 + r;
    const bool isr = col >= 1024;
    const int hcol = col & 1023;
#pragma unroll
    for (int j = 0; j < 4; ++j) {
      const int m = m0 + kq * 4 + j;
      float v = acc[ni][j];
      v += gx ? (float)gx[(size_t)m * 3072 + col] : bias[col];
      const float sg = 1.f / (1.f + __expf(-v));
      if (isr)
        rhout[(size_t)m * 1024 + hcol] = (bf16)(sg * hmast[(size_t)m * 1024 + hcol]);
      else
        zout[(size_t)m * 1024 + hcol] = sg;
    }
  }
}

// ---------------- per-step g kernel ----------------
// pre = A1@B1^T [+ A2@B2^T] + addend ; g=tanh ; h = z*hp + (1-z)*g
__global__ __launch_bounds__(256) void k_g(const bf16* __restrict__ A1, const bf16* __restrict__ B1,
                                           const bf16* __restrict__ A2, const bf16* __restrict__ B2,
                                           const bf16* __restrict__ gx,    // addend cols 2048.. , or null
                                           const float* __restrict__ bias, // per-col addend (if gx null)
                                           const float* __restrict__ zin,
                                           const float* __restrict__ hmast_in,
                                           float* __restrict__ hmast_out,
                                           bf16* __restrict__ hbout) {
  const int lane = threadIdx.x & 63;
  const int gw = blockIdx.x * 4 + (threadIdx.x >> 6);
  const int tm = gw >> 5, tn = gw & 31;  // N=1024 -> 32 n-tiles of 32
  const int m0 = tm * 16, n0 = tn * 32;
  const int r = lane & 15, kq = lane >> 4;
  f32x4 acc[2] = {};
  for (int k0 = 0; k0 < 1024; k0 += 32) {
    const int k = k0 + kq * 8;
    bf16x8 a = ldfrag(A1 + (size_t)(m0 + r) * 1024 + k);
#pragma unroll
    for (int ni = 0; ni < 2; ++ni) {
      bf16x8 b = ldfrag(B1 + (size_t)(n0 + ni * 16 + r) * 1024 + k);
      acc[ni] = MFMA16(a, b, acc[ni]);
    }
  }
  if (A2) {
    for (int k0 = 0; k0 < 1024; k0 += 32) {
      const int k = k0 + kq * 8;
      bf16x8 a = ldfrag(A2 + (size_t)(m0 + r) * 1024 + k);
#pragma unroll
      for (int ni = 0; ni < 2; ++ni) {
        bf16x8 b = ldfrag(B2 + (size_t)(n0 + ni * 16 + r) * 1024 + k);
        acc[ni] = MFMA16(a, b, acc[ni]);
      }
    }
  }
#pragma unroll
  for (int ni = 0; ni < 2; ++ni) {
    const int col = n0 + ni * 16 + r;
#pragma unroll
    for (int j = 0; j < 4; ++j) {
      const int m = m0 + kq * 4 + j;
      float v = acc[ni][j];
      v += gx ? (float)gx[(size_t)m * 3072 + 2048 + col] : bias[col];
      const float g = tanhf(v);
      const size_t idx = (size_t)m * 1024 + col;
      const float z = zin[idx];
      const float hp = hmast_in[idx];
      const float hn = z * hp + (1.f - z) * g;
      hmast_out[idx] = hn;
      hbout[idx] = (bf16)hn;
    }
  }
}

// ---------------- final output GEMM: h1_all @ Why^T + by ----------------
__global__ __launch_bounds__(256) void k_out(const bf16* __restrict__ h1, const bf16* __restrict__ why,
                                             const float* __restrict__ by, float* __restrict__ out) {
  const int lane = threadIdx.x & 63;
  const int gw = blockIdx.x * 4 + (threadIdx.x >> 6);
  const int tm = gw >> 4, tn = gw & 15;  // M=65536 (1024 tiles), N=1024 (16 tiles of 64)
  const int m0 = tm * 64, n0 = tn * 64;
  const int r = lane & 15, kq = lane >> 4;
  f32x4 acc[4][4] = {};
  for (int k0 = 0; k0 < 1024; k0 += 32) {
    const int k = k0 + kq * 8;
    bf16x8 a[4], b[4];
#pragma unroll
    for (int mi = 0; mi < 4; ++mi) a[mi] = ldfrag(h1 + (size_t)(m0 + mi * 16 + r) * 1024 + k);
#pragma unroll
    for (int ni = 0; ni < 4; ++ni) b[ni] = ldfrag(why + (size_t)(n0 + ni * 16 + r) * 1024 + k);
#pragma unroll
    for (int mi = 0; mi < 4; ++mi)
#pragma unroll
      for (int ni = 0; ni < 4; ++ni) acc[mi][ni] = MFMA16(a[mi], b[ni], acc[mi][ni]);
  }
#pragma unroll
  for (int mi = 0; mi < 4; ++mi) {
#pragma unroll
    for (int j = 0; j < 4; ++j) {
      const int m = m0 + mi * 16 + kq * 4 + j;
      const int s = m >> 7, bb = m & 127;
#pragma unroll
      for (int ni = 0; ni < 4; ++ni) {
        const int col = n0 + ni * 16 + r;
        out[((size_t)bb * 512 + s) * 1024 + col] = acc[mi][ni][j] + by[col];
      }
    }
  }
}

// ---------------- hidden state epilogue ----------------
__global__ void k_hidden(const float* __restrict__ h0m, const float* __restrict__ h1m,
                         float* __restrict__ out) {
  const int i = blockIdx.x * blockDim.x + threadIdx.x;  // 128*1024
  const int b = i >> 10, h = i & 1023;
  out[(size_t)b * 2048 + h] = h0m[i];
  out[(size_t)b * 2048 + 1024 + h] = h1m[i];
}

extern "C" void kernel_launch(void* const* d_in, const int* in_sizes, int n_in,
                              void* d_out, int out_size, void* d_ws, size_t ws_size,
                              hipStream_t stream) {
  const float* x = (const float*)d_in[0];
  const float* Wx = (const float*)d_in[1];
  const float* Wh = (const float*)d_in[2];
  const float* bh = (const float*)d_in[3];
  const float* Why = (const float*)d_in[4];
  const float* by = (const float*)d_in[5];
  float* out = (float*)d_out;

  char* ws = (char*)d_ws;
  size_t off = 0;
  auto alloc = [&](size_t bytes) -> void* {
    void* p = ws + off;
    off += (bytes + 255) & ~(size_t)255;
    return p;
  };
  const size_t WN = 2u * 3u * 1024u * 1024u;  // per-weight-tensor elems (Wx/Wh)
  bf16* Wxb = (bf16*)alloc(WN * 2);
  bf16* Whb = (bf16*)alloc(WN * 2);
  bf16* Whyb = (bf16*)alloc((size_t)1024 * 1024 * 2);
  bf16* gx0 = (bf16*)alloc((size_t)512 * 128 * 3072 * 2);       // 384 MB
  bf16* h1all = (bf16*)alloc((size_t)513 * 128 * 1024 * 2);     // slot 0 = zeros
  bf16* h0b = (bf16*)alloc((size_t)128 * 1024 * 2);
  float* h0m = (float*)alloc((size_t)128 * 1024 * 4);
  float* h1m = (float*)alloc((size_t)128 * 1024 * 4);
  float* z0 = (float*)alloc((size_t)128 * 1024 * 4);
  float* z1 = (float*)alloc((size_t)128 * 1024 * 4);
  bf16* rh0 = (bf16*)alloc((size_t)128 * 1024 * 2);
  bf16* rh1 = (bf16*)alloc((size_t)128 * 1024 * 2);
  (void)ws_size;

  // weight casts
  k_cast4<<<512, 256, 0, stream>>>(Wx, Wxb, (int)(WN / 4));
  k_cast4<<<512, 256, 0, stream>>>(Wh, Whb, (int)(WN / 4));
  k_cast4<<<256, 256, 0, stream>>>(Why, Whyb, (1024 * 1024) / 4);

  // zero initial states
  hipMemsetAsync(h0b, 0, (size_t)128 * 1024 * 2, stream);
  hipMemsetAsync(h0m, 0, (size_t)128 * 1024 * 4, stream);
  hipMemsetAsync(h1m, 0, (size_t)128 * 1024 * 4, stream);
  hipMemsetAsync(h1all, 0, (size_t)128 * 1024 * 2, stream);  // slot 0

  // gx0 = x @ Wx0^T + bh0 : 49152 waves / 4 = 12288 blocks
  k_gx0<<<12288, 256, 0, stream>>>(x, Wxb, bh, gx0);

  const size_t HB = (size_t)128 * 1024;  // per-step h elems
  const bf16* Wx1zr = Wxb + 3145728;                  // layer1, gates z,r
  const bf16* Wx1g = Wxb + 3145728 + 2097152;         // layer1, gate g
  const bf16* Wh0zr = Whb;                            // layer0 z,r
  const bf16* Wh0g = Whb + 2097152;                   // layer0 g
  const bf16* Wh1zr = Whb + 3145728;                  // layer1 z,r
  const bf16* Wh1g = Whb + 3145728 + 2097152;         // layer1 g

  for (int t = 0; t < 512; ++t) {
    const bf16* gxt = gx0 + (size_t)t * 128 * 3072;
    // L0: z,r
    k_zr<<<128, 256, 0, stream>>>(h0b, Wh0zr, nullptr, nullptr, gxt, nullptr, h0m, z0, rh0);
    // L0: g + update
    k_g<<<64, 256, 0, stream>>>(rh0, Wh0g, nullptr, nullptr, gxt, nullptr, z0, h0m, h0m, h0b);
    // L1: z,r  (input part h0b@Wx1 + recurrent h1@Wh1)
    k_zr<<<128, 256, 0, stream>>>(h0b, Wx1zr, h1all + (size_t)t * HB, Wh1zr, nullptr, bh + 3072,
                                  h1m, z1, rh1);
    // L1: g + update -> h1all slot t+1
    k_g<<<64, 256, 0, stream>>>(h0b, Wx1g, rh1, Wh1g, nullptr, bh + 5120, z1, h1m, h1m,
                                h1all + (size_t)(t + 1) * HB);
  }

  // layer_output = h1all[1..512] @ Why^T + by : 16384 waves / 4 = 4096 blocks
  k_out<<<4096, 256, 0, stream>>>(h1all + HB, Whyb, by, out);
  // hidden_state
  k_hidden<<<512, 256, 0, stream>>>(h0m, h1m, out + (size_t)128 * 512 * 1024);
}